// Round 9
// baseline (380.745 us; speedup 1.0000x reference)
//
#include <hip/hip_runtime.h>
#include <hip/hip_bf16.h>

typedef __hip_bfloat16 bf16;
typedef short bf16x8 __attribute__((ext_vector_type(8)));
typedef float f32x4 __attribute__((ext_vector_type(4)));

static __device__ __forceinline__ unsigned short f2bf(float f) {
    unsigned u = __float_as_uint(f);
    return (unsigned short)((u + 0x7fffu + ((u >> 16) & 1u)) >> 16);
}
static __device__ __forceinline__ unsigned pack2(float lo, float hi) {
    return (((unsigned)f2bf(hi)) << 16) | (unsigned)f2bf(lo);
}
static __device__ __forceinline__ float bflo(unsigned u) { return __uint_as_float(u << 16); }
static __device__ __forceinline__ float bfhi(unsigned u) { return __uint_as_float(u & 0xffff0000u); }

// ---------------------------------------------------------------------------
// Kernel 1: separable positional-encoding tables (all f32).
// ---------------------------------------------------------------------------
__global__ __launch_bounds__(256) void enc_tables(
    const float* __restrict__ Wq, const float* __restrict__ bq,
    const float* __restrict__ Wk, const float* __restrict__ bk,
    float* __restrict__ EQc, float* __restrict__ EQr,
    float* __restrict__ EKc, float* __restrict__ EKr)
{
    const int c   = blockIdx.x;
    const int ch  = threadIdx.x & 127;
    const int isk = threadIdx.x >> 7;
    const float* W = isk ? Wk : Wq;
    const float* b = isk ? bk : bq;
    const float FSTEP = (float)(3.14 / 200.0);
    float accC = 0.f, accR = 0.f;
    for (int fi = 0; fi < 32; ++fi) {
        float f = (float)fi * FSTEP;
        float a = (float)c * f;
        float s = sinf(a), co = cosf(a);
        accC = fmaf(s,  W[fi * 128 + ch],        accC);
        accC = fmaf(co, W[(32 + fi) * 128 + ch], accC);
        accR = fmaf(s,  W[(64 + fi) * 128 + ch], accR);
        accR = fmaf(co, W[(96 + fi) * 128 + ch], accR);
    }
    accR += b[ch];
    (isk ? EKc : EQc)[c * 128 + ch] = accC;
    (isk ? EKr : EQr)[c * 128 + ch] = accR;
}

// ---------------------------------------------------------------------------
// Kernel 1b: transpose+convert weights: WT[j][n][k] = W_j[k][n] as bf16.
// j: 0=Wq 1=Wk 2=Wv 3=Wo
// ---------------------------------------------------------------------------
__global__ __launch_bounds__(128) void prep_w(
    const float* __restrict__ Wq, const float* __restrict__ Wk,
    const float* __restrict__ Wv, const float* __restrict__ Wo,
    unsigned short* __restrict__ WT)
{
    const int j = blockIdx.x;       // 0..3
    const int n = blockIdx.y;       // 0..127
    const int k = threadIdx.x;      // 0..127
    const float* W = (j == 0) ? Wq : ((j == 1) ? Wk : ((j == 2) ? Wv : Wo));
    WT[((size_t)j * 128 + n) * 128 + k] = f2bf(W[k * 128 + n]);
}

// ---------------------------------------------------------------------------
// Kernel 2: fused QKV GEMM via MFMA, swapped operands: D[ch][tok]=mfma(W,x).
// ONE x staging per block, then loop nb in {q,k,v}. Grid 1280 = 5 blocks/CU
// exactly co-resident (32 KB LDS). W A-frags from global WT (L2-hot).
// ---------------------------------------------------------------------------
__global__ __launch_bounds__(256, 5) void qkv_mfma(
    const float* __restrict__ x,
    const unsigned short* __restrict__ WT,
    const float* __restrict__ EQc, const float* __restrict__ EQr,
    const float* __restrict__ EKc, const float* __restrict__ EKr,
    const float* __restrict__ bv,
    unsigned short* __restrict__ qb, unsigned short* __restrict__ kb,
    unsigned short* __restrict__ vb)
{
    __shared__ unsigned short xs[128 * 128];   // 32 KB, swizzled [tok][k]
    const int tid = threadIdx.x;
    const int mb = blockIdx.x;    // 0..1279

    // stage x tile (f32 -> bf16, swizzled): 2048 chunks of 8 elems
    const float* xbase = x + (size_t)mb * (128 * 128);
#pragma unroll
    for (int i = 0; i < 8; ++i) {
        int idx = tid + i * 256;
        int m = idx >> 4, c8 = (idx & 15) << 3;
        float4 f0 = *(const float4*)(xbase + m * 128 + c8);
        float4 f1 = *(const float4*)(xbase + m * 128 + c8 + 4);
        unsigned off = (unsigned)(m * 256 + ((c8 * 2) ^ ((m & 7) << 4)));
        unsigned* d = (unsigned*)((char*)xs + off);
        d[0] = pack2(f0.x, f0.y); d[1] = pack2(f0.z, f0.w);
        d[2] = pack2(f1.x, f1.y); d[3] = pack2(f1.z, f1.w);
    }

    const int lane = tid & 63;
    const int wv4  = tid >> 6;          // wave id 0..3
    const int il = lane & 15, g = lane >> 4;
    const int chb = wv4 << 5;           // wave's 32-channel base
    const int lx = (il & 7) << 4;
    const int rowimg = mb & 127;

    __syncthreads();

    for (int nb = 0; nb < 3; ++nb) {
        // prefetch A-fragments (W rows = output channels) from global WT
        const unsigned short* wsrc = WT + (size_t)nb * (128 * 128);
        bf16x8 aw[2][4];
#pragma unroll
        for (int ct = 0; ct < 2; ++ct)
#pragma unroll
            for (int ks = 0; ks < 4; ++ks)
                aw[ct][ks] = *(const bf16x8*)(wsrc + (chb + ct * 16 + il) * 128 + ks * 32 + g * 8);

        // MFMA main: acc[mt][ct] = D[ch-tile ct][token-tile mt]
        f32x4 acc[8][2] = {};
#pragma unroll
        for (int ks = 0; ks < 4; ++ks) {
            const int kb0 = ks * 64 + g * 16;
#pragma unroll
            for (int mt = 0; mt < 8; ++mt) {
                bf16x8 bx = *(const bf16x8*)((const char*)xs + (mt * 16 + il) * 256 + (kb0 ^ lx));
                acc[mt][0] = __builtin_amdgcn_mfma_f32_16x16x32_bf16(aw[0][ks], bx, acc[mt][0], 0, 0, 0);
                acc[mt][1] = __builtin_amdgcn_mfma_f32_16x16x32_bf16(aw[1][ks], bx, acc[mt][1], 0, 0, 0);
            }
        }

        // epilogue: lane holds token = mt*16+il, channels ch0..ch0+3
        const float* Ec = (nb == 0) ? EQc : EKc;
        const float* Er = (nb == 0) ? EQr : EKr;
        unsigned short* dstp = (nb == 0) ? qb : ((nb == 1) ? kb : vb);
#pragma unroll
        for (int ct = 0; ct < 2; ++ct) {
            const int ch0 = chb + ct * 16 + (g << 2);
            float4 er;
            if (nb < 2) er = *(const float4*)(Er + rowimg * 128 + ch0);
            else        er = *(const float4*)(bv + ch0);
#pragma unroll
            for (int mt = 0; mt < 8; ++mt) {
                const int m = mt * 16 + il;
                float v0 = acc[mt][ct][0], v1 = acc[mt][ct][1];
                float v2 = acc[mt][ct][2], v3 = acc[mt][ct][3];
                if (nb < 2) {
                    float4 ec = *(const float4*)(Ec + m * 128 + ch0);
                    v0 += ec.x + er.x; v1 += ec.y + er.y;
                    v2 += ec.z + er.z; v3 += ec.w + er.w;
                } else {
                    v0 += er.x; v1 += er.y; v2 += er.z; v3 += er.w;
                }
                uint2 o;
                o.x = pack2(v0, v1);
                o.y = pack2(v2, v3);
                *(uint2*)(dstp + ((size_t)mb * 128 + m) * 128 + ch0) = o;
            }
        }
    }
}

// ---------------------------------------------------------------------------
// Kernel 3: windowed attention + O-proj, full MFMA (unchanged from round 7).
// ---------------------------------------------------------------------------
__global__ __launch_bounds__(512) void attn_o_mfma(
    const unsigned short* __restrict__ qb, const unsigned short* __restrict__ kb,
    const unsigned short* __restrict__ vb,
    const unsigned short* __restrict__ WoT, const float* __restrict__ bo,
    float* __restrict__ out)
{
    __shared__ __align__(16) char smem[55296];
    const int QOFF = 0, KOFF = 18432, VOFF = 36864, AOOFF = 36864;

    const int w = blockIdx.x;       // 0..255
    const int b = blockIdx.y;       // 0..9
    const int wy = w >> 4, wx = w & 15;
    const int g4 = b >> 1;          // bn = 2
    int swy = wy, swx = wx;
    if (g4 == 0)      { if (wy < 15) swy = wy + 1; }   // up
    else if (g4 == 1) { if (wy > 0)  swy = wy - 1; }   // down
    else if (g4 == 2) { if (wx < 15) swx = wx + 1; }   // left
    else if (g4 == 3) { if (wx > 0)  swx = wx - 1; }   // right
    const int tid = threadIdx.x;
    const size_t bbase = (size_t)b * 16384;

#pragma unroll
    for (int i = 0; i < 2; ++i) {
        int idx = tid + i * 512;
        int m = idx >> 4, c8 = (idx & 15) << 3;
        int qt = ((wy * 8 + (m >> 3)) << 7) + (wx << 3) + (m & 7);
        uint4 rq = *(const uint4*)(qb + (bbase + qt) * 128 + c8);
        *(uint4*)(smem + QOFF + m * 288 + c8 * 2) = rq;
        int kt = ((swy * 8 + (m >> 3)) << 7) + (swx << 3) + (m & 7);
        uint4 rk = *(const uint4*)(kb + (bbase + kt) * 128 + c8);
        *(uint4*)(smem + KOFF + m * 288 + c8 * 2) = rk;
    }
#pragma unroll
    for (int i = 0; i < 2; ++i) {
        int tok = tid & 63, cs = (tid >> 6) + i * 8;
        int c8 = cs << 3;
        int vt = ((swy * 8 + (tok >> 3)) << 7) + (swx << 3) + (tok & 7);
        uint4 rv = *(const uint4*)(vb + (bbase + vt) * 128 + c8);
        unsigned short e[8] = {
            (unsigned short)rv.x, (unsigned short)(rv.x >> 16),
            (unsigned short)rv.y, (unsigned short)(rv.y >> 16),
            (unsigned short)rv.z, (unsigned short)(rv.z >> 16),
            (unsigned short)rv.w, (unsigned short)(rv.w >> 16) };
#pragma unroll
        for (int t2 = 0; t2 < 8; ++t2)
            *(unsigned short*)(smem + VOFF + (c8 + t2) * 144 + tok * 2) = e[t2];
    }
    __syncthreads();   // (1)

    const int lane = tid & 63;
    const int w8 = tid >> 6;
    const int h = w8 >> 1, half = w8 & 1;
    const int il = lane & 15, g = lane >> 4;
    const int cbase = h * 64 + g * 16;

    bf16x8 ak[4], bq2[2];
#pragma unroll
    for (int mj = 0; mj < 4; ++mj)
        ak[mj] = *(const bf16x8*)(smem + KOFF + (mj * 16 + il) * 288 + cbase);
#pragma unroll
    for (int nt = 0; nt < 2; ++nt)
        bq2[nt] = *(const bf16x8*)(smem + QOFF + ((2 * half + nt) * 16 + il) * 288 + cbase);
    f32x4 s[4][2] = {};
#pragma unroll
    for (int mj = 0; mj < 4; ++mj)
#pragma unroll
        for (int nt = 0; nt < 2; ++nt)
            s[mj][nt] = __builtin_amdgcn_mfma_f32_16x16x32_bf16(ak[mj], bq2[nt], s[mj][nt], 0, 0, 0);

    const float scale = 0.17677669529663689f;
    float p[4][2][4];
    float csum[2] = {0.f, 0.f};
#pragma unroll
    for (int mj = 0; mj < 4; ++mj)
#pragma unroll
        for (int nt = 0; nt < 2; ++nt)
#pragma unroll
            for (int r = 0; r < 4; ++r) {
                float e = __expf(s[mj][nt][r] * scale);
                p[mj][nt][r] = e;
                csum[nt] += e;
            }
#pragma unroll
    for (int nt = 0; nt < 2; ++nt) {
        csum[nt] += __shfl_xor(csum[nt], 16);
        csum[nt] += __shfl_xor(csum[nt], 32);
    }
    float inv[2] = {1.f / csum[0], 1.f / csum[1]};

    __syncthreads();   // (2)

    {
        char* pb = smem + h * 9216;
#pragma unroll
        for (int nt = 0; nt < 2; ++nt) {
            int i = (2 * half + nt) * 16 + il;
#pragma unroll
            for (int mj = 0; mj < 4; ++mj) {
                unsigned w0 = pack2(p[mj][nt][0] * inv[nt], p[mj][nt][1] * inv[nt]);
                unsigned w1 = pack2(p[mj][nt][2] * inv[nt], p[mj][nt][3] * inv[nt]);
                char* base = pb + i * 144 + mj * 32 + g * 8;
                *(unsigned*)base = w0;
                *(unsigned*)(base + 4) = w1;
            }
        }
    }

    f32x4 apv[2][2] = {};
#pragma unroll
    for (int ks = 0; ks < 2; ++ks) {
        bf16x8 av[2], bp[2];
#pragma unroll
        for (int mc = 0; mc < 2; ++mc)
            av[mc] = *(const bf16x8*)(smem + VOFF + (h * 32 + mc * 16 + il) * 144 + ks * 64 + g * 16);
#pragma unroll
        for (int nt = 0; nt < 2; ++nt)
            bp[nt] = *(const bf16x8*)(smem + h * 9216 + ((2 * half + nt) * 16 + il) * 144 + ks * 64 + g * 16);
#pragma unroll
        for (int mc = 0; mc < 2; ++mc)
#pragma unroll
            for (int nt = 0; nt < 2; ++nt)
                apv[mc][nt] = __builtin_amdgcn_mfma_f32_16x16x32_bf16(av[mc], bp[nt], apv[mc][nt], 0, 0, 0);
    }
    __syncthreads();   // (3)

#pragma unroll
    for (int nt = 0; nt < 2; ++nt) {
        int i = (2 * half + nt) * 16 + il;
#pragma unroll
        for (int mc = 0; mc < 2; ++mc) {
            int c0 = h * 32 + mc * 16 + g * 4;
            unsigned w0 = pack2(apv[mc][nt][0], apv[mc][nt][1]);
            unsigned w1 = pack2(apv[mc][nt][2], apv[mc][nt][3]);
            char* base = smem + AOOFF + i * 272 + c0 * 2;
            *(unsigned*)base = w0;
            *(unsigned*)(base + 4) = w1;
        }
    }
    __syncthreads();   // (4)

    bf16x8 awo[4];
#pragma unroll
    for (int ks = 0; ks < 4; ++ks)
        awo[ks] = *(const bf16x8*)(WoT + (16 * w8 + il) * 128 + ks * 32 + g * 8);
    f32x4 aco[4] = {};
#pragma unroll
    for (int ks = 0; ks < 4; ++ks) {
#pragma unroll
        for (int nt = 0; nt < 4; ++nt) {
            bf16x8 bao = *(const bf16x8*)(smem + AOOFF + (nt * 16 + il) * 272 + ks * 64 + g * 16);
            aco[nt] = __builtin_amdgcn_mfma_f32_16x16x32_bf16(awo[ks], bao, aco[nt], 0, 0, 0);
        }
    }

    float bov[4];
#pragma unroll
    for (int r = 0; r < 4; ++r) bov[r] = bo[16 * w8 + g * 4 + r];
    float* ols = (float*)smem;
#pragma unroll
    for (int nt = 0; nt < 4; ++nt)
#pragma unroll
        for (int r = 0; r < 4; ++r)
            ols[(nt * 16 + il) * 136 + 16 * w8 + g * 4 + r] = aco[nt][r] + bov[r];
    __syncthreads();   // (5)

#pragma unroll
    for (int i = 0; i < 4; ++i) {
        int idx = tid + i * 512;
        int m = idx >> 5, c4 = (idx & 31) << 2;
        float4 o4 = *(const float4*)&ols[m * 136 + c4];
        int tok = ((wy * 8 + (m >> 3)) << 7) + (wx << 3) + (m & 7);
        *(float4*)(out + (bbase + tok) * 128 + c4) = o4;
    }
}

// ---------------------------------------------------------------------------
extern "C" void kernel_launch(void* const* d_in, const int* in_sizes, int n_in,
                              void* d_out, int out_size, void* d_ws, size_t ws_size,
                              hipStream_t stream)
{
    const float* x  = (const float*)d_in[0];
    const float* Wq = (const float*)d_in[1];
    const float* bq = (const float*)d_in[2];
    const float* Wk = (const float*)d_in[3];
    const float* bk = (const float*)d_in[4];
    const float* Wv = (const float*)d_in[5];
    const float* bv = (const float*)d_in[6];
    const float* Wo = (const float*)d_in[7];
    const float* bo = (const float*)d_in[8];

    char* ws = (char*)d_ws;
    float* EQc = (float*)(ws);                       //  65,536 B
    float* EQr = (float*)(ws + 65536);               //  65,536 B
    float* EKc = (float*)(ws + 131072);              //  65,536 B
    float* EKr = (float*)(ws + 196608);              //  65,536 B
    unsigned short* WT = (unsigned short*)(ws + 262144);   // 131,072 B (4x128x128 bf16)
    unsigned short* qb = (unsigned short*)(ws + 393216);   // 41,943,040 B
    unsigned short* kb = (unsigned short*)(ws + 42336256); // 41,943,040 B
    unsigned short* vb = (unsigned short*)(ws + 84279296); // 41,943,040 B (end 126,222,336)
    float* outp = (float*)d_out;

    enc_tables <<<dim3(128),      256, 0, stream>>>(Wq, bq, Wk, bk, EQc, EQr, EKc, EKr);
    prep_w     <<<dim3(4, 128),   128, 0, stream>>>(Wq, Wk, Wv, Wo, WT);
    qkv_mfma   <<<dim3(1280),     256, 0, stream>>>(x, WT, EQc, EQr, EKc, EKr, bv, qb, kb, vb);
    attn_o_mfma<<<dim3(256, 10),  512, 0, stream>>>(qb, kb, vb, WT + 3 * 16384, bo, outp);
}

// Round 10
// 197.906 us; speedup vs baseline: 1.9239x; 1.9239x over previous
//
#include <hip/hip_runtime.h>
#include <hip/hip_bf16.h>

typedef __hip_bfloat16 bf16;
typedef short bf16x8 __attribute__((ext_vector_type(8)));
typedef float f32x4 __attribute__((ext_vector_type(4)));

static __device__ __forceinline__ unsigned short f2bf(float f) {
    unsigned u = __float_as_uint(f);
    return (unsigned short)((u + 0x7fffu + ((u >> 16) & 1u)) >> 16);
}
static __device__ __forceinline__ unsigned pack2(float lo, float hi) {
    return (((unsigned)f2bf(hi)) << 16) | (unsigned)f2bf(lo);
}
static __device__ __forceinline__ float bflo(unsigned u) { return __uint_as_float(u << 16); }
static __device__ __forceinline__ float bfhi(unsigned u) { return __uint_as_float(u & 0xffff0000u); }

// ---------------------------------------------------------------------------
// Kernel 1: separable positional-encoding tables (all f32).
// ---------------------------------------------------------------------------
__global__ __launch_bounds__(256) void enc_tables(
    const float* __restrict__ Wq, const float* __restrict__ bq,
    const float* __restrict__ Wk, const float* __restrict__ bk,
    float* __restrict__ EQc, float* __restrict__ EQr,
    float* __restrict__ EKc, float* __restrict__ EKr)
{
    const int c   = blockIdx.x;
    const int ch  = threadIdx.x & 127;
    const int isk = threadIdx.x >> 7;
    const float* W = isk ? Wk : Wq;
    const float* b = isk ? bk : bq;
    const float FSTEP = (float)(3.14 / 200.0);
    float accC = 0.f, accR = 0.f;
    for (int fi = 0; fi < 32; ++fi) {
        float f = (float)fi * FSTEP;
        float a = (float)c * f;
        float s = sinf(a), co = cosf(a);
        accC = fmaf(s,  W[fi * 128 + ch],        accC);
        accC = fmaf(co, W[(32 + fi) * 128 + ch], accC);
        accR = fmaf(s,  W[(64 + fi) * 128 + ch], accR);
        accR = fmaf(co, W[(96 + fi) * 128 + ch], accR);
    }
    accR += b[ch];
    (isk ? EKc : EQc)[c * 128 + ch] = accC;
    (isk ? EKr : EQr)[c * 128 + ch] = accR;
}

// ---------------------------------------------------------------------------
// Kernel 1b: transpose+convert weights: WT[j][n][k] = W_j[k][n] as bf16.
// j: 0=Wq 1=Wk 2=Wv 3=Wo
// ---------------------------------------------------------------------------
__global__ __launch_bounds__(128) void prep_w(
    const float* __restrict__ Wq, const float* __restrict__ Wk,
    const float* __restrict__ Wv, const float* __restrict__ Wo,
    unsigned short* __restrict__ WT)
{
    const int j = blockIdx.x;       // 0..3
    const int n = blockIdx.y;       // 0..127
    const int k = threadIdx.x;      // 0..127
    const float* W = (j == 0) ? Wq : ((j == 1) ? Wk : ((j == 2) ? Wv : Wo));
    WT[((size_t)j * 128 + n) * 128 + k] = f2bf(W[k * 128 + n]);
}

// ---------------------------------------------------------------------------
// Kernel 1c: x -> bf16 (streaming convert; RNE identical to prior staging).
// 20,971,520 elems = 2,621,440 chunks of 8; 2048x256 thr x 5 iters.
// ---------------------------------------------------------------------------
__global__ __launch_bounds__(256) void x2bf(
    const float* __restrict__ x, unsigned short* __restrict__ xbf)
{
    int idx = blockIdx.x * 256 + threadIdx.x;
    const int total = 2621440;
#pragma unroll 1
    for (; idx < total; idx += 2048 * 256) {
        const float* s = x + (size_t)idx * 8;
        float4 f0 = *(const float4*)(s);
        float4 f1 = *(const float4*)(s + 4);
        uint4 o;
        o.x = pack2(f0.x, f0.y); o.y = pack2(f0.z, f0.w);
        o.z = pack2(f1.x, f1.y); o.w = pack2(f1.z, f1.w);
        *(uint4*)(xbf + (size_t)idx * 8) = o;
    }
}

// ---------------------------------------------------------------------------
// Kernel 2: streaming QKV GEMM via MFMA, swapped operands: D[ch][tok]=mfma(W,x).
// NO LDS, NO barriers. B-frags read directly from bf16 xbf (L3-resident),
// A-frags from L2-hot WT. acc split in two mt-halves to keep VGPR ~110.
// ---------------------------------------------------------------------------
__global__ __launch_bounds__(256, 3) void qkv_mfma(
    const unsigned short* __restrict__ xbf,
    const unsigned short* __restrict__ WT,
    const float* __restrict__ EQc, const float* __restrict__ EQr,
    const float* __restrict__ EKc, const float* __restrict__ EKr,
    const float* __restrict__ bv,
    unsigned short* __restrict__ qb, unsigned short* __restrict__ kb,
    unsigned short* __restrict__ vb)
{
    const int tid = threadIdx.x;
    const int mb = blockIdx.x;    // 0..1279
    const int nb = blockIdx.y;    // 0: q, 1: k, 2: v

    const int lane = tid & 63;
    const int wv4  = tid >> 6;          // wave id 0..3
    const int il = lane & 15, g = lane >> 4;
    const int chb = wv4 << 5;           // wave's 32-channel base
    const int rowimg = mb & 127;

    // A-fragments (W rows = output channels) from global WT (L2-hot)
    const unsigned short* wsrc = WT + (size_t)nb * (128 * 128);
    bf16x8 aw[2][4];
#pragma unroll
    for (int ct = 0; ct < 2; ++ct)
#pragma unroll
        for (int ks = 0; ks < 4; ++ks)
            aw[ct][ks] = *(const bf16x8*)(wsrc + (chb + ct * 16 + il) * 128 + ks * 32 + g * 8);

    const unsigned short* xt = xbf + (size_t)mb * (128 * 128);
    const float* Ec = (nb == 0) ? EQc : EKc;
    const float* Er = (nb == 0) ? EQr : EKr;
    unsigned short* dstp = (nb == 0) ? qb : ((nb == 1) ? kb : vb);

#pragma unroll
    for (int half = 0; half < 2; ++half) {
        // MFMA: acc[mt4][ct], B-frags straight from global
        f32x4 acc[4][2] = {};
#pragma unroll
        for (int ks = 0; ks < 4; ++ks) {
            bf16x8 bx[4];
#pragma unroll
            for (int mt4 = 0; mt4 < 4; ++mt4)
                bx[mt4] = *(const bf16x8*)(xt + (half * 64 + mt4 * 16 + il) * 128 + ks * 32 + g * 8);
#pragma unroll
            for (int mt4 = 0; mt4 < 4; ++mt4) {
                acc[mt4][0] = __builtin_amdgcn_mfma_f32_16x16x32_bf16(aw[0][ks], bx[mt4], acc[mt4][0], 0, 0, 0);
                acc[mt4][1] = __builtin_amdgcn_mfma_f32_16x16x32_bf16(aw[1][ks], bx[mt4], acc[mt4][1], 0, 0, 0);
            }
        }
        // epilogue: lane holds token m = half*64+mt4*16+il, channels ch0..ch0+3
#pragma unroll
        for (int ct = 0; ct < 2; ++ct) {
            const int ch0 = chb + ct * 16 + (g << 2);
            float4 er;
            if (nb < 2) er = *(const float4*)(Er + rowimg * 128 + ch0);
            else        er = *(const float4*)(bv + ch0);
#pragma unroll
            for (int mt4 = 0; mt4 < 4; ++mt4) {
                const int m = half * 64 + mt4 * 16 + il;
                float v0 = acc[mt4][ct][0], v1 = acc[mt4][ct][1];
                float v2 = acc[mt4][ct][2], v3 = acc[mt4][ct][3];
                if (nb < 2) {
                    float4 ec = *(const float4*)(Ec + m * 128 + ch0);
                    v0 += ec.x + er.x; v1 += ec.y + er.y;
                    v2 += ec.z + er.z; v3 += ec.w + er.w;
                } else {
                    v0 += er.x; v1 += er.y; v2 += er.z; v3 += er.w;
                }
                uint2 o;
                o.x = pack2(v0, v1);
                o.y = pack2(v2, v3);
                *(uint2*)(dstp + ((size_t)mb * 128 + m) * 128 + ch0) = o;
            }
        }
    }
}

// ---------------------------------------------------------------------------
// Kernel 3: windowed attention + O-proj, full MFMA (unchanged from round 8).
// ---------------------------------------------------------------------------
__global__ __launch_bounds__(512) void attn_o_mfma(
    const unsigned short* __restrict__ qb, const unsigned short* __restrict__ kb,
    const unsigned short* __restrict__ vb,
    const unsigned short* __restrict__ WoT, const float* __restrict__ bo,
    float* __restrict__ out)
{
    __shared__ __align__(16) char smem[55296];
    const int QOFF = 0, KOFF = 18432, VOFF = 36864, AOOFF = 36864;

    const int w = blockIdx.x;       // 0..255
    const int b = blockIdx.y;       // 0..9
    const int wy = w >> 4, wx = w & 15;
    const int g4 = b >> 1;          // bn = 2
    int swy = wy, swx = wx;
    if (g4 == 0)      { if (wy < 15) swy = wy + 1; }   // up
    else if (g4 == 1) { if (wy > 0)  swy = wy - 1; }   // down
    else if (g4 == 2) { if (wx < 15) swx = wx + 1; }   // left
    else if (g4 == 3) { if (wx > 0)  swx = wx - 1; }   // right
    const int tid = threadIdx.x;
    const size_t bbase = (size_t)b * 16384;

#pragma unroll
    for (int i = 0; i < 2; ++i) {
        int idx = tid + i * 512;
        int m = idx >> 4, c8 = (idx & 15) << 3;
        int qt = ((wy * 8 + (m >> 3)) << 7) + (wx << 3) + (m & 7);
        uint4 rq = *(const uint4*)(qb + (bbase + qt) * 128 + c8);
        *(uint4*)(smem + QOFF + m * 288 + c8 * 2) = rq;
        int kt = ((swy * 8 + (m >> 3)) << 7) + (swx << 3) + (m & 7);
        uint4 rk = *(const uint4*)(kb + (bbase + kt) * 128 + c8);
        *(uint4*)(smem + KOFF + m * 288 + c8 * 2) = rk;
    }
#pragma unroll
    for (int i = 0; i < 2; ++i) {
        int tok = tid & 63, cs = (tid >> 6) + i * 8;
        int c8 = cs << 3;
        int vt = ((swy * 8 + (tok >> 3)) << 7) + (swx << 3) + (tok & 7);
        uint4 rv = *(const uint4*)(vb + (bbase + vt) * 128 + c8);
        unsigned short e[8] = {
            (unsigned short)rv.x, (unsigned short)(rv.x >> 16),
            (unsigned short)rv.y, (unsigned short)(rv.y >> 16),
            (unsigned short)rv.z, (unsigned short)(rv.z >> 16),
            (unsigned short)rv.w, (unsigned short)(rv.w >> 16) };
#pragma unroll
        for (int t2 = 0; t2 < 8; ++t2)
            *(unsigned short*)(smem + VOFF + (c8 + t2) * 144 + tok * 2) = e[t2];
    }
    __syncthreads();   // (1)

    const int lane = tid & 63;
    const int w8 = tid >> 6;
    const int h = w8 >> 1, half = w8 & 1;
    const int il = lane & 15, g = lane >> 4;
    const int cbase = h * 64 + g * 16;

    bf16x8 ak[4], bq2[2];
#pragma unroll
    for (int mj = 0; mj < 4; ++mj)
        ak[mj] = *(const bf16x8*)(smem + KOFF + (mj * 16 + il) * 288 + cbase);
#pragma unroll
    for (int nt = 0; nt < 2; ++nt)
        bq2[nt] = *(const bf16x8*)(smem + QOFF + ((2 * half + nt) * 16 + il) * 288 + cbase);
    f32x4 s[4][2] = {};
#pragma unroll
    for (int mj = 0; mj < 4; ++mj)
#pragma unroll
        for (int nt = 0; nt < 2; ++nt)
            s[mj][nt] = __builtin_amdgcn_mfma_f32_16x16x32_bf16(ak[mj], bq2[nt], s[mj][nt], 0, 0, 0);

    const float scale = 0.17677669529663689f;
    float p[4][2][4];
    float csum[2] = {0.f, 0.f};
#pragma unroll
    for (int mj = 0; mj < 4; ++mj)
#pragma unroll
        for (int nt = 0; nt < 2; ++nt)
#pragma unroll
            for (int r = 0; r < 4; ++r) {
                float e = __expf(s[mj][nt][r] * scale);
                p[mj][nt][r] = e;
                csum[nt] += e;
            }
#pragma unroll
    for (int nt = 0; nt < 2; ++nt) {
        csum[nt] += __shfl_xor(csum[nt], 16);
        csum[nt] += __shfl_xor(csum[nt], 32);
    }
    float inv[2] = {1.f / csum[0], 1.f / csum[1]};

    __syncthreads();   // (2)

    {
        char* pb = smem + h * 9216;
#pragma unroll
        for (int nt = 0; nt < 2; ++nt) {
            int i = (2 * half + nt) * 16 + il;
#pragma unroll
            for (int mj = 0; mj < 4; ++mj) {
                unsigned w0 = pack2(p[mj][nt][0] * inv[nt], p[mj][nt][1] * inv[nt]);
                unsigned w1 = pack2(p[mj][nt][2] * inv[nt], p[mj][nt][3] * inv[nt]);
                char* base = pb + i * 144 + mj * 32 + g * 8;
                *(unsigned*)base = w0;
                *(unsigned*)(base + 4) = w1;
            }
        }
    }

    f32x4 apv[2][2] = {};
#pragma unroll
    for (int ks = 0; ks < 2; ++ks) {
        bf16x8 av[2], bp[2];
#pragma unroll
        for (int mc = 0; mc < 2; ++mc)
            av[mc] = *(const bf16x8*)(smem + VOFF + (h * 32 + mc * 16 + il) * 144 + ks * 64 + g * 16);
#pragma unroll
        for (int nt = 0; nt < 2; ++nt)
            bp[nt] = *(const bf16x8*)(smem + h * 9216 + ((2 * half + nt) * 16 + il) * 144 + ks * 64 + g * 16);
#pragma unroll
        for (int mc = 0; mc < 2; ++mc)
#pragma unroll
            for (int nt = 0; nt < 2; ++nt)
                apv[mc][nt] = __builtin_amdgcn_mfma_f32_16x16x32_bf16(av[mc], bp[nt], apv[mc][nt], 0, 0, 0);
    }
    __syncthreads();   // (3)

#pragma unroll
    for (int nt = 0; nt < 2; ++nt) {
        int i = (2 * half + nt) * 16 + il;
#pragma unroll
        for (int mc = 0; mc < 2; ++mc) {
            int c0 = h * 32 + mc * 16 + g * 4;
            unsigned w0 = pack2(apv[mc][nt][0], apv[mc][nt][1]);
            unsigned w1 = pack2(apv[mc][nt][2], apv[mc][nt][3]);
            char* base = smem + AOOFF + i * 272 + c0 * 2;
            *(unsigned*)base = w0;
            *(unsigned*)(base + 4) = w1;
        }
    }
    __syncthreads();   // (4)

    bf16x8 awo[4];
#pragma unroll
    for (int ks = 0; ks < 4; ++ks)
        awo[ks] = *(const bf16x8*)(WoT + (16 * w8 + il) * 128 + ks * 32 + g * 8);
    f32x4 aco[4] = {};
#pragma unroll
    for (int ks = 0; ks < 4; ++ks) {
#pragma unroll
        for (int nt = 0; nt < 4; ++nt) {
            bf16x8 bao = *(const bf16x8*)(smem + AOOFF + (nt * 16 + il) * 272 + ks * 64 + g * 16);
            aco[nt] = __builtin_amdgcn_mfma_f32_16x16x32_bf16(awo[ks], bao, aco[nt], 0, 0, 0);
        }
    }

    float bov[4];
#pragma unroll
    for (int r = 0; r < 4; ++r) bov[r] = bo[16 * w8 + g * 4 + r];
    float* ols = (float*)smem;
#pragma unroll
    for (int nt = 0; nt < 4; ++nt)
#pragma unroll
        for (int r = 0; r < 4; ++r)
            ols[(nt * 16 + il) * 136 + 16 * w8 + g * 4 + r] = aco[nt][r] + bov[r];
    __syncthreads();   // (5)

#pragma unroll
    for (int i = 0; i < 4; ++i) {
        int idx = tid + i * 512;
        int m = idx >> 5, c4 = (idx & 31) << 2;
        float4 o4 = *(const float4*)&ols[m * 136 + c4];
        int tok = ((wy * 8 + (m >> 3)) << 7) + (wx << 3) + (m & 7);
        *(float4*)(out + (bbase + tok) * 128 + c4) = o4;
    }
}

// ---------------------------------------------------------------------------
extern "C" void kernel_launch(void* const* d_in, const int* in_sizes, int n_in,
                              void* d_out, int out_size, void* d_ws, size_t ws_size,
                              hipStream_t stream)
{
    const float* x  = (const float*)d_in[0];
    const float* Wq = (const float*)d_in[1];
    const float* bq = (const float*)d_in[2];
    const float* Wk = (const float*)d_in[3];
    const float* bk = (const float*)d_in[4];
    const float* Wv = (const float*)d_in[5];
    const float* bv = (const float*)d_in[6];
    const float* Wo = (const float*)d_in[7];
    const float* bo = (const float*)d_in[8];

    char* ws = (char*)d_ws;
    float* EQc = (float*)(ws);                        //  65,536 B
    float* EQr = (float*)(ws + 65536);                //  65,536 B
    float* EKc = (float*)(ws + 131072);               //  65,536 B
    float* EKr = (float*)(ws + 196608);               //  65,536 B
    unsigned short* WT  = (unsigned short*)(ws + 262144);    // 131,072 B
    unsigned short* xbf = (unsigned short*)(ws + 393216);    // 41,943,040 B
    unsigned short* qb  = (unsigned short*)(ws + 42336256);  // 41,943,040 B
    unsigned short* kb  = (unsigned short*)(ws + 84279296);  // 41,943,040 B
    unsigned short* vb  = (unsigned short*)(ws + 126222336); // 41,943,040 B (end 168,165,376)
    float* outp = (float*)d_out;

    enc_tables <<<dim3(128),      256, 0, stream>>>(Wq, bq, Wk, bk, EQc, EQr, EKc, EKr);
    prep_w     <<<dim3(4, 128),   128, 0, stream>>>(Wq, Wk, Wv, Wo, WT);
    x2bf       <<<dim3(2048),     256, 0, stream>>>(x, xbf);
    qkv_mfma   <<<dim3(1280, 3),  256, 0, stream>>>(xbf, WT, EQc, EQr, EKc, EKr, bv, qb, kb, vb);
    attn_o_mfma<<<dim3(256, 10),  512, 0, stream>>>(qb, kb, vb, WT + 3 * 16384, bo, outp);
}

// Round 11
// 141.484 us; speedup vs baseline: 2.6911x; 1.3988x over previous
//
#include <hip/hip_runtime.h>
#include <hip/hip_bf16.h>

typedef __hip_bfloat16 bf16;
typedef short bf16x8 __attribute__((ext_vector_type(8)));
typedef float f32x4 __attribute__((ext_vector_type(4)));

static __device__ __forceinline__ unsigned short f2bf(float f) {
    unsigned u = __float_as_uint(f);
    return (unsigned short)((u + 0x7fffu + ((u >> 16) & 1u)) >> 16);
}
static __device__ __forceinline__ unsigned pack2(float lo, float hi) {
    return (((unsigned)f2bf(hi)) << 16) | (unsigned)f2bf(lo);
}
static __device__ __forceinline__ float bflo(unsigned u) { return __uint_as_float(u << 16); }
static __device__ __forceinline__ float bfhi(unsigned u) { return __uint_as_float(u & 0xffff0000u); }

// ---------------------------------------------------------------------------
// Kernel 1: separable positional-encoding tables (all f32).
// ---------------------------------------------------------------------------
__global__ __launch_bounds__(256) void enc_tables(
    const float* __restrict__ Wq, const float* __restrict__ bq,
    const float* __restrict__ Wk, const float* __restrict__ bk,
    float* __restrict__ EQc, float* __restrict__ EQr,
    float* __restrict__ EKc, float* __restrict__ EKr)
{
    const int c   = blockIdx.x;
    const int ch  = threadIdx.x & 127;
    const int isk = threadIdx.x >> 7;
    const float* W = isk ? Wk : Wq;
    const float* b = isk ? bk : bq;
    const float FSTEP = (float)(3.14 / 200.0);
    float accC = 0.f, accR = 0.f;
    for (int fi = 0; fi < 32; ++fi) {
        float f = (float)fi * FSTEP;
        float a = (float)c * f;
        float s = sinf(a), co = cosf(a);
        accC = fmaf(s,  W[fi * 128 + ch],        accC);
        accC = fmaf(co, W[(32 + fi) * 128 + ch], accC);
        accR = fmaf(s,  W[(64 + fi) * 128 + ch], accR);
        accR = fmaf(co, W[(96 + fi) * 128 + ch], accR);
    }
    accR += b[ch];
    (isk ? EKc : EQc)[c * 128 + ch] = accC;
    (isk ? EKr : EQr)[c * 128 + ch] = accR;
}

// ---------------------------------------------------------------------------
// Kernel 1b: transpose+convert weights: WT[j][n][k] = W_j[k][n] as bf16.
// j: 0=Wq 1=Wk 2=Wv 3=Wo
// ---------------------------------------------------------------------------
__global__ __launch_bounds__(128) void prep_w(
    const float* __restrict__ Wq, const float* __restrict__ Wk,
    const float* __restrict__ Wv, const float* __restrict__ Wo,
    unsigned short* __restrict__ WT)
{
    const int j = blockIdx.x;       // 0..3
    const int n = blockIdx.y;       // 0..127
    const int k = threadIdx.x;      // 0..127
    const float* W = (j == 0) ? Wq : ((j == 1) ? Wk : ((j == 2) ? Wv : Wo));
    WT[((size_t)j * 128 + n) * 128 + k] = f2bf(W[k * 128 + n]);
}

// ---------------------------------------------------------------------------
// Kernel 2: QKV GEMM via MFMA, swapped operands D[ch][tok]=mfma(W,x), with
// LDS-transpose epilogue for coalesced stores. Round-8 skeleton + new epilogue.
// ---------------------------------------------------------------------------
__global__ __launch_bounds__(256, 4) void qkv_mfma(
    const float* __restrict__ x,
    const unsigned short* __restrict__ WT,
    const float* __restrict__ EQc, const float* __restrict__ EQr,
    const float* __restrict__ EKc, const float* __restrict__ EKr,
    const float* __restrict__ bv,
    unsigned short* __restrict__ qb, unsigned short* __restrict__ kb,
    unsigned short* __restrict__ vb)
{
    __shared__ unsigned short xs[128 * 128];   // 32 KB, swizzled [tok][k]; reused for output
    const int tid = threadIdx.x;
    const int mb = blockIdx.x;    // 0..1279
    const int nb = blockIdx.y;    // 0: q, 1: k, 2: v

    // stage x tile (f32 -> bf16, swizzled): 2048 chunks of 8 elems
    const float* xbase = x + (size_t)mb * (128 * 128);
#pragma unroll
    for (int i = 0; i < 8; ++i) {
        int idx = tid + i * 256;
        int m = idx >> 4, c8 = (idx & 15) << 3;
        float4 f0 = *(const float4*)(xbase + m * 128 + c8);
        float4 f1 = *(const float4*)(xbase + m * 128 + c8 + 4);
        unsigned off = (unsigned)(m * 256 + ((c8 * 2) ^ ((m & 7) << 4)));
        unsigned* d = (unsigned*)((char*)xs + off);
        d[0] = pack2(f0.x, f0.y); d[1] = pack2(f0.z, f0.w);
        d[2] = pack2(f1.x, f1.y); d[3] = pack2(f1.z, f1.w);
    }

    const int lane = tid & 63;
    const int wv4  = tid >> 6;          // wave id 0..3
    const int il = lane & 15, g = lane >> 4;
    const int chb = wv4 << 5;           // wave's 32-channel base

    // prefetch A-fragments (W rows = output channels) from global WT (L2-hot)
    const unsigned short* wsrc = WT + (size_t)nb * (128 * 128);
    bf16x8 aw[2][4];
#pragma unroll
    for (int ct = 0; ct < 2; ++ct)
#pragma unroll
        for (int ks = 0; ks < 4; ++ks)
            aw[ct][ks] = *(const bf16x8*)(wsrc + (chb + ct * 16 + il) * 128 + ks * 32 + g * 8);

    __syncthreads();

    // MFMA main: acc[mt][ct] = D[ch-tile ct][token-tile mt]
    const int lx = (il & 7) << 4;
    f32x4 acc[8][2] = {};
#pragma unroll
    for (int ks = 0; ks < 4; ++ks) {
        const int kb0 = ks * 64 + g * 16;
#pragma unroll
        for (int mt = 0; mt < 8; ++mt) {
            bf16x8 bx = *(const bf16x8*)((const char*)xs + (mt * 16 + il) * 256 + (kb0 ^ lx));
            acc[mt][0] = __builtin_amdgcn_mfma_f32_16x16x32_bf16(aw[0][ks], bx, acc[mt][0], 0, 0, 0);
            acc[mt][1] = __builtin_amdgcn_mfma_f32_16x16x32_bf16(aw[1][ks], bx, acc[mt][1], 0, 0, 0);
        }
    }

    __syncthreads();   // all xs reads done; reuse xs for transposed output

    // epilogue part 1: add enc in f32, pack bf16, write transposed into xs.
    // lane holds token m = mt*16+il, channels ch0..ch0+3; LDS row = token.
    const int rowimg = mb & 127;
    const float* Ec = (nb == 0) ? EQc : EKc;
    const float* Er = (nb == 0) ? EQr : EKr;
#pragma unroll
    for (int ct = 0; ct < 2; ++ct) {
        const int ch0 = chb + ct * 16 + (g << 2);
        float4 er;
        if (nb < 2) er = *(const float4*)(Er + rowimg * 128 + ch0);
        else        er = *(const float4*)(bv + ch0);
#pragma unroll
        for (int mt = 0; mt < 8; ++mt) {
            const int m = mt * 16 + il;
            float v0 = acc[mt][ct][0], v1 = acc[mt][ct][1];
            float v2 = acc[mt][ct][2], v3 = acc[mt][ct][3];
            if (nb < 2) {
                float4 ec = *(const float4*)(Ec + m * 128 + ch0);
                v0 += ec.x + er.x; v1 += ec.y + er.y;
                v2 += ec.z + er.z; v3 += ec.w + er.w;
            } else {
                v0 += er.x; v1 += er.y; v2 += er.z; v3 += er.w;
            }
            unsigned off = (unsigned)(m * 256 + ((ch0 * 2) ^ ((m & 7) << 4)));
            unsigned* d = (unsigned*)((char*)xs + off);
            d[0] = pack2(v0, v1);
            d[1] = pack2(v2, v3);
        }
    }
    __syncthreads();

    // epilogue part 2: cooperative coalesced store (16 lanes = one 256B row)
    unsigned short* dstp = (nb == 0) ? qb : ((nb == 1) ? kb : vb);
#pragma unroll
    for (int i = 0; i < 8; ++i) {
        int idx = tid + i * 256;
        int m = idx >> 4, cb16 = (idx & 15) << 4;   // byte col in row
        uint4 v = *(const uint4*)((const char*)xs + m * 256 + (cb16 ^ ((m & 7) << 4)));
        *(uint4*)(dstp + ((size_t)mb * 128 + m) * 128 + (idx & 15) * 8) = v;
    }
}

// ---------------------------------------------------------------------------
// Kernel 3: windowed attention + O-proj, full MFMA (unchanged from round 8).
// ---------------------------------------------------------------------------
__global__ __launch_bounds__(512) void attn_o_mfma(
    const unsigned short* __restrict__ qb, const unsigned short* __restrict__ kb,
    const unsigned short* __restrict__ vb,
    const unsigned short* __restrict__ WoT, const float* __restrict__ bo,
    float* __restrict__ out)
{
    __shared__ __align__(16) char smem[55296];
    const int QOFF = 0, KOFF = 18432, VOFF = 36864, AOOFF = 36864;

    const int w = blockIdx.x;       // 0..255
    const int b = blockIdx.y;       // 0..9
    const int wy = w >> 4, wx = w & 15;
    const int g4 = b >> 1;          // bn = 2
    int swy = wy, swx = wx;
    if (g4 == 0)      { if (wy < 15) swy = wy + 1; }   // up
    else if (g4 == 1) { if (wy > 0)  swy = wy - 1; }   // down
    else if (g4 == 2) { if (wx < 15) swx = wx + 1; }   // left
    else if (g4 == 3) { if (wx > 0)  swx = wx - 1; }   // right
    const int tid = threadIdx.x;
    const size_t bbase = (size_t)b * 16384;

#pragma unroll
    for (int i = 0; i < 2; ++i) {
        int idx = tid + i * 512;
        int m = idx >> 4, c8 = (idx & 15) << 3;
        int qt = ((wy * 8 + (m >> 3)) << 7) + (wx << 3) + (m & 7);
        uint4 rq = *(const uint4*)(qb + (bbase + qt) * 128 + c8);
        *(uint4*)(smem + QOFF + m * 288 + c8 * 2) = rq;
        int kt = ((swy * 8 + (m >> 3)) << 7) + (swx << 3) + (m & 7);
        uint4 rk = *(const uint4*)(kb + (bbase + kt) * 128 + c8);
        *(uint4*)(smem + KOFF + m * 288 + c8 * 2) = rk;
    }
#pragma unroll
    for (int i = 0; i < 2; ++i) {
        int tok = tid & 63, cs = (tid >> 6) + i * 8;
        int c8 = cs << 3;
        int vt = ((swy * 8 + (tok >> 3)) << 7) + (swx << 3) + (tok & 7);
        uint4 rv = *(const uint4*)(vb + (bbase + vt) * 128 + c8);
        unsigned short e[8] = {
            (unsigned short)rv.x, (unsigned short)(rv.x >> 16),
            (unsigned short)rv.y, (unsigned short)(rv.y >> 16),
            (unsigned short)rv.z, (unsigned short)(rv.z >> 16),
            (unsigned short)rv.w, (unsigned short)(rv.w >> 16) };
#pragma unroll
        for (int t2 = 0; t2 < 8; ++t2)
            *(unsigned short*)(smem + VOFF + (c8 + t2) * 144 + tok * 2) = e[t2];
    }
    __syncthreads();   // (1)

    const int lane = tid & 63;
    const int w8 = tid >> 6;
    const int h = w8 >> 1, half = w8 & 1;
    const int il = lane & 15, g = lane >> 4;
    const int cbase = h * 64 + g * 16;

    bf16x8 ak[4], bq2[2];
#pragma unroll
    for (int mj = 0; mj < 4; ++mj)
        ak[mj] = *(const bf16x8*)(smem + KOFF + (mj * 16 + il) * 288 + cbase);
#pragma unroll
    for (int nt = 0; nt < 2; ++nt)
        bq2[nt] = *(const bf16x8*)(smem + QOFF + ((2 * half + nt) * 16 + il) * 288 + cbase);
    f32x4 s[4][2] = {};
#pragma unroll
    for (int mj = 0; mj < 4; ++mj)
#pragma unroll
        for (int nt = 0; nt < 2; ++nt)
            s[mj][nt] = __builtin_amdgcn_mfma_f32_16x16x32_bf16(ak[mj], bq2[nt], s[mj][nt], 0, 0, 0);

    const float scale = 0.17677669529663689f;
    float p[4][2][4];
    float csum[2] = {0.f, 0.f};
#pragma unroll
    for (int mj = 0; mj < 4; ++mj)
#pragma unroll
        for (int nt = 0; nt < 2; ++nt)
#pragma unroll
            for (int r = 0; r < 4; ++r) {
                float e = __expf(s[mj][nt][r] * scale);
                p[mj][nt][r] = e;
                csum[nt] += e;
            }
#pragma unroll
    for (int nt = 0; nt < 2; ++nt) {
        csum[nt] += __shfl_xor(csum[nt], 16);
        csum[nt] += __shfl_xor(csum[nt], 32);
    }
    float inv[2] = {1.f / csum[0], 1.f / csum[1]};

    __syncthreads();   // (2)

    {
        char* pb = smem + h * 9216;
#pragma unroll
        for (int nt = 0; nt < 2; ++nt) {
            int i = (2 * half + nt) * 16 + il;
#pragma unroll
            for (int mj = 0; mj < 4; ++mj) {
                unsigned w0 = pack2(p[mj][nt][0] * inv[nt], p[mj][nt][1] * inv[nt]);
                unsigned w1 = pack2(p[mj][nt][2] * inv[nt], p[mj][nt][3] * inv[nt]);
                char* base = pb + i * 144 + mj * 32 + g * 8;
                *(unsigned*)base = w0;
                *(unsigned*)(base + 4) = w1;
            }
        }
    }

    f32x4 apv[2][2] = {};
#pragma unroll
    for (int ks = 0; ks < 2; ++ks) {
        bf16x8 av[2], bp[2];
#pragma unroll
        for (int mc = 0; mc < 2; ++mc)
            av[mc] = *(const bf16x8*)(smem + VOFF + (h * 32 + mc * 16 + il) * 144 + ks * 64 + g * 16);
#pragma unroll
        for (int nt = 0; nt < 2; ++nt)
            bp[nt] = *(const bf16x8*)(smem + h * 9216 + ((2 * half + nt) * 16 + il) * 144 + ks * 64 + g * 16);
#pragma unroll
        for (int mc = 0; mc < 2; ++mc)
#pragma unroll
            for (int nt = 0; nt < 2; ++nt)
                apv[mc][nt] = __builtin_amdgcn_mfma_f32_16x16x32_bf16(av[mc], bp[nt], apv[mc][nt], 0, 0, 0);
    }
    __syncthreads();   // (3)

#pragma unroll
    for (int nt = 0; nt < 2; ++nt) {
        int i = (2 * half + nt) * 16 + il;
#pragma unroll
        for (int mc = 0; mc < 2; ++mc) {
            int c0 = h * 32 + mc * 16 + g * 4;
            unsigned w0 = pack2(apv[mc][nt][0], apv[mc][nt][1]);
            unsigned w1 = pack2(apv[mc][nt][2], apv[mc][nt][3]);
            char* base = smem + AOOFF + i * 272 + c0 * 2;
            *(unsigned*)base = w0;
            *(unsigned*)(base + 4) = w1;
        }
    }
    __syncthreads();   // (4)

    bf16x8 awo[4];
#pragma unroll
    for (int ks = 0; ks < 4; ++ks)
        awo[ks] = *(const bf16x8*)(WoT + (16 * w8 + il) * 128 + ks * 32 + g * 8);
    f32x4 aco[4] = {};
#pragma unroll
    for (int ks = 0; ks < 4; ++ks) {
#pragma unroll
        for (int nt = 0; nt < 4; ++nt) {
            bf16x8 bao = *(const bf16x8*)(smem + AOOFF + (nt * 16 + il) * 272 + ks * 64 + g * 16);
            aco[nt] = __builtin_amdgcn_mfma_f32_16x16x32_bf16(awo[ks], bao, aco[nt], 0, 0, 0);
        }
    }

    float bov[4];
#pragma unroll
    for (int r = 0; r < 4; ++r) bov[r] = bo[16 * w8 + g * 4 + r];
    float* ols = (float*)smem;
#pragma unroll
    for (int nt = 0; nt < 4; ++nt)
#pragma unroll
        for (int r = 0; r < 4; ++r)
            ols[(nt * 16 + il) * 136 + 16 * w8 + g * 4 + r] = aco[nt][r] + bov[r];
    __syncthreads();   // (5)

#pragma unroll
    for (int i = 0; i < 4; ++i) {
        int idx = tid + i * 512;
        int m = idx >> 5, c4 = (idx & 31) << 2;
        float4 o4 = *(const float4*)&ols[m * 136 + c4];
        int tok = ((wy * 8 + (m >> 3)) << 7) + (wx << 3) + (m & 7);
        *(float4*)(out + (bbase + tok) * 128 + c4) = o4;
    }
}

// ---------------------------------------------------------------------------
extern "C" void kernel_launch(void* const* d_in, const int* in_sizes, int n_in,
                              void* d_out, int out_size, void* d_ws, size_t ws_size,
                              hipStream_t stream)
{
    const float* x  = (const float*)d_in[0];
    const float* Wq = (const float*)d_in[1];
    const float* bq = (const float*)d_in[2];
    const float* Wk = (const float*)d_in[3];
    const float* bk = (const float*)d_in[4];
    const float* Wv = (const float*)d_in[5];
    const float* bv = (const float*)d_in[6];
    const float* Wo = (const float*)d_in[7];
    const float* bo = (const float*)d_in[8];

    char* ws = (char*)d_ws;
    float* EQc = (float*)(ws);                       //  65,536 B
    float* EQr = (float*)(ws + 65536);               //  65,536 B
    float* EKc = (float*)(ws + 131072);              //  65,536 B
    float* EKr = (float*)(ws + 196608);              //  65,536 B
    unsigned short* WT = (unsigned short*)(ws + 262144);   // 131,072 B (4x128x128 bf16)
    unsigned short* qb = (unsigned short*)(ws + 393216);   // 41,943,040 B
    unsigned short* kb = (unsigned short*)(ws + 42336256); // 41,943,040 B
    unsigned short* vb = (unsigned short*)(ws + 84279296); // 41,943,040 B (end 126,222,336)
    float* outp = (float*)d_out;

    enc_tables <<<dim3(128),      256, 0, stream>>>(Wq, bq, Wk, bk, EQc, EQr, EKc, EKr);
    prep_w     <<<dim3(4, 128),   128, 0, stream>>>(Wq, Wk, Wv, Wo, WT);
    qkv_mfma   <<<dim3(1280, 3),  256, 0, stream>>>(x, WT, EQc, EQr, EKc, EKr, bv, qb, kb, vb);
    attn_o_mfma<<<dim3(256, 10),  512, 0, stream>>>(qb, kb, vb, WT + 3 * 16384, bo, outp);
}